// Round 8
// baseline (38.720 us; speedup 1.0000x reference)
//
#include <hip/hip_runtime.h>

#define DIM  128
#define TILE 512   // edges per block (256 threads)

#ifndef __has_builtin
#define __has_builtin(x) 0
#endif

__device__ __forceinline__ int dot4i8(int a, int b, int c) {
#if __has_builtin(__builtin_amdgcn_sdot4)
    return __builtin_amdgcn_sdot4(a, b, c, false);
#else
    c += ((a << 24) >> 24) * ((b << 24) >> 24);
    c += ((a << 16) >> 24) * ((b << 16) >> 24);
    c += ((a <<  8) >> 24) * ((b <<  8) >> 24);
    c += ( a        >> 24) * ( b        >> 24);
    return c;
#endif
}

// ---- per-row int8 quantization into two half-tables (same row scale) ----
// QA holds dims [0,64), QB holds dims [64,128): 16 ints (64B) per row each.
__global__ __launch_bounds__(256) void quant_rows_split_kernel(
    const float* __restrict__ h, int* __restrict__ QA, int* __restrict__ QB,
    float* __restrict__ scaleQ, int n_nodes)
{
    const int t  = threadIdx.x;
    const int l  = t & 31;
    const int rg = t >> 5;
    const int row = blockIdx.x * 8 + rg;
    if (row >= n_nodes) return;

    const float4 v = ((const float4*)h)[row * 32 + l];
    float am = fmaxf(fmaxf(fabsf(v.x), fabsf(v.y)),
                     fmaxf(fabsf(v.z), fabsf(v.w)));
    am = fmaxf(am, __shfl_xor(am, 16, 64));
    am = fmaxf(am, __shfl_xor(am,  8, 64));
    am = fmaxf(am, __shfl_xor(am,  4, 64));
    am = fmaxf(am, __shfl_xor(am,  2, 64));
    am = fmaxf(am, __shfl_xor(am,  1, 64));

    const float inv = (am > 0.0f) ? (127.0f / am) : 0.0f;
    const int q0 = (int)rintf(v.x * inv);
    const int q1 = (int)rintf(v.y * inv);
    const int q2 = (int)rintf(v.z * inv);
    const int q3 = (int)rintf(v.w * inv);
    const int packed = (q0 & 0xFF) | ((q1 & 0xFF) << 8)
                     | ((q2 & 0xFF) << 16) | ((q3 & 0xFF) << 24);
    if (l < 16) QA[row * 16 + l]        = packed;   // dims 4l..4l+3  (<64)
    else        QB[row * 16 + (l - 16)] = packed;   // dims 64+...
    if (l == 0) scaleQ[row] = am * (1.0f / 127.0f);
}

// ---- one half-dot pass: 4 lanes/edge, 64B row-half gathers, L2-resident ----
// PASS 0: partial[e]  = half-dot (exact int in float)
// PASS 1: out[e]      = (partial[e] + half-dot) * su * sv
template <int PASS>
__global__ __launch_bounds__(256) void score_half_kernel(
    const int* __restrict__ Qh,
    const float* __restrict__ scaleQ,
    const float* __restrict__ r,
    const int* __restrict__ src_idx,
    const int* __restrict__ dst_idx,
    float* __restrict__ partial,
    float* __restrict__ out,
    int n_edges)
{
    __shared__ int2 sd_tile[TILE];
    __shared__ int  s_rones;

    const int t     = threadIdx.x;
    const int tile0 = blockIdx.x * TILE;

    if (t == 0) s_rones = 1;
    #pragma unroll
    for (int k = 0; k < 2; ++k) {
        const int e = tile0 + k * 256 + t;
        int2 sd;
        sd.x = (e < n_edges) ? __builtin_nontemporal_load(src_idx + e) : 0;
        sd.y = (e < n_edges) ? __builtin_nontemporal_load(dst_idx + e) : 0;
        sd_tile[k * 256 + t] = sd;
    }
    __syncthreads();
    if (r[t & (DIM - 1)] != 1.0f) s_rones = 0;  // benign race: all write 0
    __syncthreads();

    const int lane   = t & 63;
    const int grp    = lane >> 2;   // 16 edge-groups per wave per round
    const int sub    = lane & 3;    // lane within 4-lane edge group
    const int waveid = t >> 6;
    const int ebase  = waveid * 128;
    const int4* __restrict__ Q4 = (const int4*)Qh;  // 16B = 16 int8

    // The two edges this lane finalizes (round j==sub and j==sub+4).
    const int eoff0 = ebase + sub * 16 + grp;
    const int eoff1 = ebase + (sub + 4) * 16 + grp;
    const int g0 = tile0 + eoff0;
    const int g1 = tile0 + eoff1;

    // Issue scattered/streaming loads for the finalize step early so they
    // complete under the gather burst below.
    float su0 = 1.f, sv0 = 1.f, su1 = 1.f, sv1 = 1.f;
    float prev0 = 0.f, prev1 = 0.f;
    if (PASS == 1) {
        const int2 f0 = sd_tile[eoff0];
        const int2 f1 = sd_tile[eoff1];
        su0 = scaleQ[f0.x]; sv0 = scaleQ[f0.y];
        su1 = scaleQ[f1.x]; sv1 = scaleQ[f1.y];
        prev0 = (g0 < n_edges) ? __builtin_nontemporal_load(partial + g0) : 0.f;
        prev1 = (g1 < n_edges) ? __builtin_nontemporal_load(partial + g1) : 0.f;
    }

    float res0 = 0.0f, res1 = 0.0f;

    if (s_rones) {
        // Preload all 16 half-row fragments: 16 vmem ops in flight per lane.
        int4 A[8], B[8];
        #pragma unroll
        for (int j = 0; j < 8; ++j) {
            const int2 sd = sd_tile[ebase + j * 16 + grp];
            A[j] = Q4[(size_t)sd.x * 4 + sub];
            B[j] = Q4[(size_t)sd.y * 4 + sub];
        }
        #pragma unroll
        for (int j = 0; j < 8; ++j) {
            int id = dot4i8(A[j].x, B[j].x, 0);
            id = dot4i8(A[j].y, B[j].y, id);
            id = dot4i8(A[j].z, B[j].z, id);
            id = dot4i8(A[j].w, B[j].w, id);
            // butterfly over the 4-lane group (masks 2,1 stay inside)
            id += __shfl_xor(id, 2, 64);
            id += __shfl_xor(id, 1, 64);
            if (sub == (j & 3)) {
                if (j < 4) res0 = (float)id; else res1 = (float)id;
            }
        }
    } else {
        // general-r path: float unpack honoring per-element r for this half
        float rl[16];
        #pragma unroll
        for (int k = 0; k < 4; ++k) {
            const float4 rv = ((const float4*)r)[PASS * 16 + sub * 4 + k];
            rl[4*k+0] = rv.x; rl[4*k+1] = rv.y;
            rl[4*k+2] = rv.z; rl[4*k+3] = rv.w;
        }
        #pragma unroll 2
        for (int j = 0; j < 8; ++j) {
            const int2 sd = sd_tile[ebase + j * 16 + grp];
            const int4 a = Q4[(size_t)sd.x * 4 + sub];
            const int4 b = Q4[(size_t)sd.y * 4 + sub];
            float p = 0.0f;
            const int aw[4] = {a.x, a.y, a.z, a.w};
            const int bw[4] = {b.x, b.y, b.z, b.w};
            #pragma unroll
            for (int w = 0; w < 4; ++w) {
                p += (float)((aw[w] << 24) >> 24) * (float)((bw[w] << 24) >> 24) * rl[4*w+0];
                p += (float)((aw[w] << 16) >> 24) * (float)((bw[w] << 16) >> 24) * rl[4*w+1];
                p += (float)((aw[w] <<  8) >> 24) * (float)((bw[w] <<  8) >> 24) * rl[4*w+2];
                p += (float)( aw[w]        >> 24) * (float)( bw[w]        >> 24) * rl[4*w+3];
            }
            p += __shfl_xor(p, 2, 64);
            p += __shfl_xor(p, 1, 64);
            if (sub == (j & 3)) {
                if (j < 4) res0 = p; else res1 = p;
            }
        }
    }

    if (PASS == 0) {
        if (g0 < n_edges) __builtin_nontemporal_store(res0, partial + g0);
        if (g1 < n_edges) __builtin_nontemporal_store(res1, partial + g1);
    } else {
        if (g0 < n_edges)
            __builtin_nontemporal_store((res0 + prev0) * su0 * sv0, out + g0);
        if (g1 < n_edges)
            __builtin_nontemporal_store((res1 + prev1) * su1 * sv1, out + g1);
    }
}

// ---- f32 fallback if workspace is too small (needs no scratch) ----
__global__ __launch_bounds__(256) void score_edges_f32_kernel(
    const float* __restrict__ h,
    const float* __restrict__ r,
    const int* __restrict__ src_idx,
    const int* __restrict__ dst_idx,
    float* __restrict__ out,
    int n_edges)
{
    __shared__ int2 sd_tile[256];
    const int t      = threadIdx.x;
    const int lane   = t & 63;
    const int sub    = lane & 31;
    const int halfid = t >> 5;
    const int tile0  = blockIdx.x * 256;
    {
        const int e = tile0 + t;
        int2 sd;
        sd.x = (e < n_edges) ? src_idx[e] : 0;
        sd.y = (e < n_edges) ? dst_idx[e] : 0;
        sd_tile[t] = sd;
    }
    __syncthreads();

    const float4  rc = ((const float4*)r)[sub];
    const float4* __restrict__ h4 = (const float4*)h;
    const int ebase = halfid * 32;
    float res = 0.0f;

    #pragma unroll 4
    for (int j = 0; j < 32; ++j) {
        const int2 sd = sd_tile[ebase + j];
        const float4 a = h4[(size_t)sd.x * (DIM / 4) + sub];
        const float4 b = h4[(size_t)sd.y * (DIM / 4) + sub];
        float p = (a.x * b.x) * rc.x + (a.y * b.y) * rc.y
                + (a.z * b.z) * rc.z + (a.w * b.w) * rc.w;
        p += __shfl_xor(p, 16, 64);
        p += __shfl_xor(p, 8, 64);
        p += __shfl_xor(p, 4, 64);
        p += __shfl_xor(p, 2, 64);
        p += __shfl_xor(p, 1, 64);
        if (sub == j) res = p;
    }
    const int eo = tile0 + ebase + sub;
    if (eo < n_edges) out[eo] = res;
}

extern "C" void kernel_launch(void* const* d_in, const int* in_sizes, int n_in,
                              void* d_out, int out_size, void* d_ws, size_t ws_size,
                              hipStream_t stream)
{
    const float* h       = (const float*)d_in[0];
    const float* r       = (const float*)d_in[1];
    const int*   src_idx = (const int*)d_in[2];
    const int*   dst_idx = (const int*)d_in[3];
    float*       out     = (float*)d_out;

    const int n_nodes = in_sizes[0] / DIM;
    const int n_edges = in_sizes[2];

    auto align256 = [](size_t x) { return (x + 255) & ~(size_t)255; };
    const size_t half_bytes = (size_t)n_nodes * 64;          // 16 ints/row
    const size_t qa_off = 0;
    const size_t qb_off = align256(qa_off + half_bytes);
    const size_t sc_off = align256(qb_off + half_bytes);
    const size_t pa_off = align256(sc_off + (size_t)n_nodes * sizeof(float));
    const size_t need   = pa_off + (size_t)n_edges * sizeof(float);

    if (ws_size >= need) {
        int*   QA      = (int*)((char*)d_ws + qa_off);
        int*   QB      = (int*)((char*)d_ws + qb_off);
        float* scaleQ  = (float*)((char*)d_ws + sc_off);
        float* partial = (float*)((char*)d_ws + pa_off);

        quant_rows_split_kernel<<<(n_nodes + 7) / 8, 256, 0, stream>>>(
            h, QA, QB, scaleQ, n_nodes);

        const int blocks = (n_edges + TILE - 1) / TILE;
        score_half_kernel<0><<<blocks, 256, 0, stream>>>(
            QA, scaleQ, r, src_idx, dst_idx, partial, out, n_edges);
        score_half_kernel<1><<<blocks, 256, 0, stream>>>(
            QB, scaleQ, r, src_idx, dst_idx, partial, out, n_edges);
    } else {
        const int blocks = (n_edges + 255) / 256;
        score_edges_f32_kernel<<<blocks, 256, 0, stream>>>(
            h, r, src_idx, dst_idx, out, n_edges);
    }
}

// Round 10
// 34.527 us; speedup vs baseline: 1.1215x; 1.1215x over previous
//
#include <hip/hip_runtime.h>

#define DIM  128
#define TILE 256   // edges per block

#ifndef __has_builtin
#define __has_builtin(x) 0
#endif

// Native vector types for nontemporal builtins (HIP_vector_type is rejected).
typedef float vf4 __attribute__((ext_vector_type(4)));
typedef int   vi4 __attribute__((ext_vector_type(4)));

__device__ __forceinline__ int dot4i8(int a, int b, int c) {
#if __has_builtin(__builtin_amdgcn_sdot4)
    return __builtin_amdgcn_sdot4(a, b, c, false);
#else
    c += ((a << 24) >> 24) * ((b << 24) >> 24);
    c += ((a << 16) >> 24) * ((b << 16) >> 24);
    c += ((a <<  8) >> 24) * ((b <<  8) >> 24);
    c += ( a        >> 24) * ( b        >> 24);
    return c;
#endif
}

// ---- per-row int8 quantization: 32 lanes per row, 8 rows per block ----
// h is read once -> non-temporal, so it doesn't evict the Q table from L2.
__global__ __launch_bounds__(256) void quant_rows_kernel(
    const float* __restrict__ h, int* __restrict__ Qi,
    float* __restrict__ scaleQ, int n_nodes)
{
    const int t  = threadIdx.x;
    const int l  = t & 31;
    const int rg = t >> 5;
    const int row = blockIdx.x * 8 + rg;
    if (row >= n_nodes) return;

    const vf4 v = __builtin_nontemporal_load(((const vf4*)h) + row * 32 + l);
    float am = fmaxf(fmaxf(fabsf(v.x), fabsf(v.y)),
                     fmaxf(fabsf(v.z), fabsf(v.w)));
    am = fmaxf(am, __shfl_xor(am, 16, 64));
    am = fmaxf(am, __shfl_xor(am,  8, 64));
    am = fmaxf(am, __shfl_xor(am,  4, 64));
    am = fmaxf(am, __shfl_xor(am,  2, 64));
    am = fmaxf(am, __shfl_xor(am,  1, 64));

    const float inv = (am > 0.0f) ? (127.0f / am) : 0.0f;
    const int q0 = (int)rintf(v.x * inv);
    const int q1 = (int)rintf(v.y * inv);
    const int q2 = (int)rintf(v.z * inv);
    const int q3 = (int)rintf(v.w * inv);
    Qi[row * 32 + l] = (q0 & 0xFF) | ((q1 & 0xFF) << 8)
                     | ((q2 & 0xFF) << 16) | ((q3 & 0xFF) << 24);
    if (l == 0) scaleQ[row] = am * (1.0f / 127.0f);
}

// ---- gather + dot, deep-preload: 16 row-gathers in flight per lane ----
// idx loads and out stores are single-use streams -> non-temporal;
// Qi and scaleQ stay cacheable (they are the reused working set).
__global__ __launch_bounds__(256) void score_edges_i8_v3(
    const int* __restrict__ Qi,
    const float* __restrict__ scaleQ,
    const float* __restrict__ r,
    const int* __restrict__ src_idx,
    const int* __restrict__ dst_idx,
    float* __restrict__ out,
    int n_edges)
{
    __shared__ int2 sd_tile[TILE];
    __shared__ int  s_rones;

    const int t     = threadIdx.x;
    const int tile0 = blockIdx.x * TILE;

    if (t == 0) s_rones = 1;
    {
        const int e = tile0 + t;
        int2 sd;
        sd.x = (e < n_edges) ? __builtin_nontemporal_load(src_idx + e) : 0;
        sd.y = (e < n_edges) ? __builtin_nontemporal_load(dst_idx + e) : 0;
        sd_tile[t] = sd;
    }
    __syncthreads();
    if (r[t & (DIM - 1)] != 1.0f) s_rones = 0;  // benign race: all write 0
    __syncthreads();

    const int lane   = t & 63;
    const int oct    = lane >> 3;   // which of 8 edges this lane serves per j
    const int sub    = lane & 7;    // lane within the 8-lane edge group
    const int waveid = t >> 6;
    const int ebase  = waveid * 64;
    const int4* __restrict__ Q4 = (const int4*)Qi;

    // Final-edge identity for this lane: issue the scattered scale loads
    // now so they complete under the gather burst + compute below.
    const int2  sdf = sd_tile[ebase + sub * 8 + oct];
    const float su  = scaleQ[sdf.x];
    const float sv  = scaleQ[sdf.y];

    float resf = 0.0f;

    if (s_rones) {
        // Preload ALL 16 row fragments: 16 vmem ops in flight per lane.
        int4 A[8], B[8];
        #pragma unroll
        for (int j = 0; j < 8; ++j) {
            const int2 sd = sd_tile[ebase + j * 8 + oct];
            A[j] = Q4[(size_t)sd.x * 8 + sub];
            B[j] = Q4[(size_t)sd.y * 8 + sub];
        }
        #pragma unroll
        for (int j = 0; j < 8; ++j) {
            int id = dot4i8(A[j].x, B[j].x, 0);
            id = dot4i8(A[j].y, B[j].y, id);
            id = dot4i8(A[j].z, B[j].z, id);
            id = dot4i8(A[j].w, B[j].w, id);
            id += __shfl_xor(id, 4, 64);
            id += __shfl_xor(id, 2, 64);
            id += __shfl_xor(id, 1, 64);
            if (sub == j) resf = (float)id;
        }
    } else {
        // general-r path: float unpack honoring per-element r
        float rl[16];
        #pragma unroll
        for (int k = 0; k < 4; ++k) {
            const float4 rv = ((const float4*)r)[sub * 4 + k];
            rl[4*k+0] = rv.x; rl[4*k+1] = rv.y;
            rl[4*k+2] = rv.z; rl[4*k+3] = rv.w;
        }
        #pragma unroll 2
        for (int j = 0; j < 8; ++j) {
            const int2 sd = sd_tile[ebase + j * 8 + oct];
            const int4 a = Q4[(size_t)sd.x * 8 + sub];
            const int4 b = Q4[(size_t)sd.y * 8 + sub];
            float p = 0.0f;
            const int aw[4] = {a.x, a.y, a.z, a.w};
            const int bw[4] = {b.x, b.y, b.z, b.w};
            #pragma unroll
            for (int w = 0; w < 4; ++w) {
                p += (float)((aw[w] << 24) >> 24) * (float)((bw[w] << 24) >> 24) * rl[4*w+0];
                p += (float)((aw[w] << 16) >> 24) * (float)((bw[w] << 16) >> 24) * rl[4*w+1];
                p += (float)((aw[w] <<  8) >> 24) * (float)((bw[w] <<  8) >> 24) * rl[4*w+2];
                p += (float)( aw[w]        >> 24) * (float)( bw[w]        >> 24) * rl[4*w+3];
            }
            p += __shfl_xor(p, 4, 64);
            p += __shfl_xor(p, 2, 64);
            p += __shfl_xor(p, 1, 64);
            if (sub == j) resf = p;
        }
    }

    const int eo = tile0 + ebase + sub * 8 + oct;
    if (eo < n_edges) __builtin_nontemporal_store(resf * su * sv, out + eo);
}

// ---- f32 fallback if workspace is too small (needs no scratch) ----
__global__ __launch_bounds__(256) void score_edges_f32_kernel(
    const float* __restrict__ h,
    const float* __restrict__ r,
    const int* __restrict__ src_idx,
    const int* __restrict__ dst_idx,
    float* __restrict__ out,
    int n_edges)
{
    __shared__ int2 sd_tile[TILE];
    const int t      = threadIdx.x;
    const int lane   = t & 63;
    const int sub    = lane & 31;
    const int halfid = t >> 5;
    const int tile0  = blockIdx.x * TILE;
    {
        const int e = tile0 + t;
        int2 sd;
        sd.x = (e < n_edges) ? src_idx[e] : 0;
        sd.y = (e < n_edges) ? dst_idx[e] : 0;
        sd_tile[t] = sd;
    }
    __syncthreads();

    const float4  rc = ((const float4*)r)[sub];
    const float4* __restrict__ h4 = (const float4*)h;
    const int ebase = halfid * 32;
    float res = 0.0f;

    #pragma unroll 4
    for (int j = 0; j < 32; ++j) {
        const int2 sd = sd_tile[ebase + j];
        const float4 a = h4[(size_t)sd.x * (DIM / 4) + sub];
        const float4 b = h4[(size_t)sd.y * (DIM / 4) + sub];
        float p = (a.x * b.x) * rc.x + (a.y * b.y) * rc.y
                + (a.z * b.z) * rc.z + (a.w * b.w) * rc.w;
        p += __shfl_xor(p, 16, 64);
        p += __shfl_xor(p, 8, 64);
        p += __shfl_xor(p, 4, 64);
        p += __shfl_xor(p, 2, 64);
        p += __shfl_xor(p, 1, 64);
        if (sub == j) res = p;
    }
    const int eo = tile0 + ebase + sub;
    if (eo < n_edges) out[eo] = res;
}

extern "C" void kernel_launch(void* const* d_in, const int* in_sizes, int n_in,
                              void* d_out, int out_size, void* d_ws, size_t ws_size,
                              hipStream_t stream)
{
    const float* h       = (const float*)d_in[0];
    const float* r       = (const float*)d_in[1];
    const int*   src_idx = (const int*)d_in[2];
    const int*   dst_idx = (const int*)d_in[3];
    float*       out     = (float*)d_out;

    const int n_nodes = in_sizes[0] / DIM;
    const int n_edges = in_sizes[2];
    const int blocks  = (n_edges + TILE - 1) / TILE;

    const size_t q_bytes  = (size_t)n_nodes * DIM;            // int8 rows
    const size_t q_al     = (q_bytes + 255) & ~(size_t)255;
    const size_t sc_off   = q_al;
    const size_t sc_bytes = (size_t)n_nodes * sizeof(float);
    const size_t need     = sc_off + sc_bytes;

    if (ws_size >= need) {
        int*   Qi     = (int*)d_ws;
        float* scaleQ = (float*)((char*)d_ws + sc_off);

        quant_rows_kernel<<<(n_nodes + 7) / 8, 256, 0, stream>>>(
            h, Qi, scaleQ, n_nodes);
        score_edges_i8_v3<<<blocks, 256, 0, stream>>>(
            Qi, scaleQ, r, src_idx, dst_idx, out, n_edges);
    } else {
        score_edges_f32_kernel<<<blocks, 256, 0, stream>>>(
            h, r, src_idx, dst_idx, out, n_edges);
    }
}

// Round 11
// 30.186 us; speedup vs baseline: 1.2827x; 1.1438x over previous
//
#include <hip/hip_runtime.h>

#define DIM  128
#define TILE 256   // edges per block

#ifndef __has_builtin
#define __has_builtin(x) 0
#endif

__device__ __forceinline__ int dot4i8(int a, int b, int c) {
#if __has_builtin(__builtin_amdgcn_sdot4)
    return __builtin_amdgcn_sdot4(a, b, c, false);
#else
    c += ((a << 24) >> 24) * ((b << 24) >> 24);
    c += ((a << 16) >> 24) * ((b << 16) >> 24);
    c += ((a <<  8) >> 24) * ((b <<  8) >> 24);
    c += ( a        >> 24) * ( b        >> 24);
    return c;
#endif
}

// ---- per-row int8 quantization: 32 lanes per row, 8 rows per block ----
__global__ __launch_bounds__(256) void quant_rows_kernel(
    const float* __restrict__ h, int* __restrict__ Qi,
    float* __restrict__ scaleQ, int n_nodes)
{
    const int t  = threadIdx.x;
    const int l  = t & 31;
    const int rg = t >> 5;
    const int row = blockIdx.x * 8 + rg;
    if (row >= n_nodes) return;

    const float4 v = ((const float4*)h)[row * 32 + l];
    float am = fmaxf(fmaxf(fabsf(v.x), fabsf(v.y)),
                     fmaxf(fabsf(v.z), fabsf(v.w)));
    am = fmaxf(am, __shfl_xor(am, 16, 64));
    am = fmaxf(am, __shfl_xor(am,  8, 64));
    am = fmaxf(am, __shfl_xor(am,  4, 64));
    am = fmaxf(am, __shfl_xor(am,  2, 64));
    am = fmaxf(am, __shfl_xor(am,  1, 64));

    const float inv = (am > 0.0f) ? (127.0f / am) : 0.0f;
    const int q0 = (int)rintf(v.x * inv);
    const int q1 = (int)rintf(v.y * inv);
    const int q2 = (int)rintf(v.z * inv);
    const int q3 = (int)rintf(v.w * inv);
    Qi[row * 32 + l] = (q0 & 0xFF) | ((q1 & 0xFF) << 8)
                     | ((q2 & 0xFF) << 16) | ((q3 & 0xFF) << 24);
    if (l == 0) scaleQ[row] = am * (1.0f / 127.0f);
}

// ---- gather + dot, deep-preload: 16 row-gathers in flight per lane ----
__global__ __launch_bounds__(256) void score_edges_i8_v3(
    const int* __restrict__ Qi,
    const float* __restrict__ scaleQ,
    const float* __restrict__ r,
    const int* __restrict__ src_idx,
    const int* __restrict__ dst_idx,
    float* __restrict__ out,
    int n_edges)
{
    __shared__ int2 sd_tile[TILE];
    __shared__ int  s_rones;

    const int t     = threadIdx.x;
    const int tile0 = blockIdx.x * TILE;

    if (t == 0) s_rones = 1;
    {
        const int e = tile0 + t;
        int2 sd;
        sd.x = (e < n_edges) ? src_idx[e] : 0;
        sd.y = (e < n_edges) ? dst_idx[e] : 0;
        sd_tile[t] = sd;
    }
    __syncthreads();
    if (r[t & (DIM - 1)] != 1.0f) s_rones = 0;  // benign race: all write 0
    __syncthreads();

    const int lane   = t & 63;
    const int oct    = lane >> 3;   // which of 8 edges this lane serves per j
    const int sub    = lane & 7;    // lane within the 8-lane edge group
    const int waveid = t >> 6;
    const int ebase  = waveid * 64;
    const int4* __restrict__ Q4 = (const int4*)Qi;

    // Final-edge identity for this lane: issue the scattered scale loads
    // now so they complete under the gather burst + compute below.
    const int2  sdf = sd_tile[ebase + sub * 8 + oct];
    const float su  = scaleQ[sdf.x];
    const float sv  = scaleQ[sdf.y];

    float resf = 0.0f;

    if (s_rones) {
        // Preload ALL 16 row fragments: 16 vmem ops in flight per lane.
        int4 A[8], B[8];
        #pragma unroll
        for (int j = 0; j < 8; ++j) {
            const int2 sd = sd_tile[ebase + j * 8 + oct];
            A[j] = Q4[(size_t)sd.x * 8 + sub];
            B[j] = Q4[(size_t)sd.y * 8 + sub];
        }
        #pragma unroll
        for (int j = 0; j < 8; ++j) {
            int id = dot4i8(A[j].x, B[j].x, 0);
            id = dot4i8(A[j].y, B[j].y, id);
            id = dot4i8(A[j].z, B[j].z, id);
            id = dot4i8(A[j].w, B[j].w, id);
            id += __shfl_xor(id, 4, 64);
            id += __shfl_xor(id, 2, 64);
            id += __shfl_xor(id, 1, 64);
            if (sub == j) resf = (float)id;
        }
    } else {
        // general-r path: float unpack honoring per-element r
        float rl[16];
        #pragma unroll
        for (int k = 0; k < 4; ++k) {
            const float4 rv = ((const float4*)r)[sub * 4 + k];
            rl[4*k+0] = rv.x; rl[4*k+1] = rv.y;
            rl[4*k+2] = rv.z; rl[4*k+3] = rv.w;
        }
        #pragma unroll 2
        for (int j = 0; j < 8; ++j) {
            const int2 sd = sd_tile[ebase + j * 8 + oct];
            const int4 a = Q4[(size_t)sd.x * 8 + sub];
            const int4 b = Q4[(size_t)sd.y * 8 + sub];
            float p = 0.0f;
            const int aw[4] = {a.x, a.y, a.z, a.w};
            const int bw[4] = {b.x, b.y, b.z, b.w};
            #pragma unroll
            for (int w = 0; w < 4; ++w) {
                p += (float)((aw[w] << 24) >> 24) * (float)((bw[w] << 24) >> 24) * rl[4*w+0];
                p += (float)((aw[w] << 16) >> 24) * (float)((bw[w] << 16) >> 24) * rl[4*w+1];
                p += (float)((aw[w] <<  8) >> 24) * (float)((bw[w] <<  8) >> 24) * rl[4*w+2];
                p += (float)( aw[w]        >> 24) * (float)( bw[w]        >> 24) * rl[4*w+3];
            }
            p += __shfl_xor(p, 4, 64);
            p += __shfl_xor(p, 2, 64);
            p += __shfl_xor(p, 1, 64);
            if (sub == j) resf = p;
        }
    }

    const int eo = tile0 + ebase + sub * 8 + oct;
    if (eo < n_edges) out[eo] = resf * su * sv;
}

// ---- f32 fallback if workspace is too small (needs no scratch) ----
__global__ __launch_bounds__(256) void score_edges_f32_kernel(
    const float* __restrict__ h,
    const float* __restrict__ r,
    const int* __restrict__ src_idx,
    const int* __restrict__ dst_idx,
    float* __restrict__ out,
    int n_edges)
{
    __shared__ int2 sd_tile[TILE];
    const int t      = threadIdx.x;
    const int lane   = t & 63;
    const int sub    = lane & 31;
    const int halfid = t >> 5;
    const int tile0  = blockIdx.x * TILE;
    {
        const int e = tile0 + t;
        int2 sd;
        sd.x = (e < n_edges) ? src_idx[e] : 0;
        sd.y = (e < n_edges) ? dst_idx[e] : 0;
        sd_tile[t] = sd;
    }
    __syncthreads();

    const float4  rc = ((const float4*)r)[sub];
    const float4* __restrict__ h4 = (const float4*)h;
    const int ebase = halfid * 32;
    float res = 0.0f;

    #pragma unroll 4
    for (int j = 0; j < 32; ++j) {
        const int2 sd = sd_tile[ebase + j];
        const float4 a = h4[(size_t)sd.x * (DIM / 4) + sub];
        const float4 b = h4[(size_t)sd.y * (DIM / 4) + sub];
        float p = (a.x * b.x) * rc.x + (a.y * b.y) * rc.y
                + (a.z * b.z) * rc.z + (a.w * b.w) * rc.w;
        p += __shfl_xor(p, 16, 64);
        p += __shfl_xor(p, 8, 64);
        p += __shfl_xor(p, 4, 64);
        p += __shfl_xor(p, 2, 64);
        p += __shfl_xor(p, 1, 64);
        if (sub == j) res = p;
    }
    const int eo = tile0 + ebase + sub;
    if (eo < n_edges) out[eo] = res;
}

extern "C" void kernel_launch(void* const* d_in, const int* in_sizes, int n_in,
                              void* d_out, int out_size, void* d_ws, size_t ws_size,
                              hipStream_t stream)
{
    const float* h       = (const float*)d_in[0];
    const float* r       = (const float*)d_in[1];
    const int*   src_idx = (const int*)d_in[2];
    const int*   dst_idx = (const int*)d_in[3];
    float*       out     = (float*)d_out;

    const int n_nodes = in_sizes[0] / DIM;
    const int n_edges = in_sizes[2];
    const int blocks  = (n_edges + TILE - 1) / TILE;

    const size_t q_bytes  = (size_t)n_nodes * DIM;            // int8 rows
    const size_t q_al     = (q_bytes + 255) & ~(size_t)255;
    const size_t sc_off   = q_al;
    const size_t sc_bytes = (size_t)n_nodes * sizeof(float);
    const size_t need     = sc_off + sc_bytes;

    if (ws_size >= need) {
        int*   Qi     = (int*)d_ws;
        float* scaleQ = (float*)((char*)d_ws + sc_off);

        quant_rows_kernel<<<(n_nodes + 7) / 8, 256, 0, stream>>>(
            h, Qi, scaleQ, n_nodes);
        score_edges_i8_v3<<<blocks, 256, 0, stream>>>(
            Qi, scaleQ, r, src_idx, dst_idx, out, n_edges);
    } else {
        score_edges_f32_kernel<<<blocks, 256, 0, stream>>>(
            h, r, src_idx, dst_idx, out, n_edges);
    }
}